// Round 4
// baseline (13514.482 us; speedup 1.0000x reference)
//
#include <hip/hip_runtime.h>
#include <stdint.h>

#define CRF_B 128
#define CRF_T 256
#define CRF_K 600
#define HALF_K 300
#define FWD_NT 640          // 10 waves
#define NWAVE 10
#define NG 8                // i-groups
#define RI 75               // rows per i-group (NG*RI = 600)
#define RS 6                // lognorm rescale interval

// ---------------- prep: expT[i,j] = bf16(exp(trans[i,j])), zero sync flags ----------------
__global__ __launch_bounds__(256) void prep_kernel(const float* __restrict__ trans,
                                                   uint16_t* __restrict__ expT,
                                                   int* __restrict__ xflag)
{
    int idx = blockIdx.x * 256 + threadIdx.x;
    if (idx < 256) xflag[idx] = 0;                 // reset handshake flags every launch
    if (idx < CRF_K * CRF_K) {
        float e = __expf(trans[idx]);
        uint32_t u = __float_as_uint(e);
        u += 0x7fffu + ((u >> 16) & 1u);           // RNE to bf16
        expT[idx] = (uint16_t)(u >> 16);
    }
}

// ---------------- gold-path score: unary + binary ----------------
__global__ __launch_bounds__(64) void score_kernel(const float* __restrict__ pot,
                                                   const float* __restrict__ trans,
                                                   const int* __restrict__ tags,
                                                   const int* __restrict__ seq_len,
                                                   float* __restrict__ scoreArr)
{
    int b = blockIdx.x;
    int lane = threadIdx.x;
    int L = seq_len[b];
    float s = 0.f;
    for (int t = lane; t < CRF_T; t += 64) {
        if (t < L) {
            int tg = tags[b * CRF_T + t];
            s += pot[((size_t)b * CRF_T + t) * CRF_K + tg];
            if (t >= 1) {
                int tp = tags[b * CRF_T + t - 1];
                s += trans[tp * CRF_K + tg];
            }
        }
    }
    for (int o = 32; o; o >>= 1) s += __shfl_down(s, o);
    if (lane == 0) scoreArr[b] = s;
}

// xbuf float offset for (role, pair, parity, half, problem) — 300 floats per slot
__device__ __forceinline__ size_t xoff(int role, int pair, int par, int half, int p)
{
    return ((((size_t)((role * 64 + pair) * 2 + par)) * 2 + half) * 2 + p) * HALF_K;
}

// ---------------- fused forward: NB=2 problems x j-half split, paired-block exchange ----------------
// blocks 0..127  : Viterbi role   (exact f32 max-plus + backpointers)
// blocks 128..255: lognorm role   (scaled-exp forward with bf16 expT)
// pairing: idx^8 (same XCD under %8 round-robin); pairIdx -> problems (2p, 2p+1)
__global__ __launch_bounds__(FWD_NT) void fwd_kernel(
    const float* __restrict__ pot,
    const float* __restrict__ trans,
    const uint16_t* __restrict__ expT,
    const int* __restrict__ seq_len,
    uint16_t* __restrict__ bp,
    float* __restrict__ lognormArr,
    int* __restrict__ lastArr,
    float* __restrict__ xbuf,
    int* __restrict__ xflag)
{
    const int bid = blockIdx.x;
    const bool isVit = bid < CRF_B;
    const int role = isVit ? 0 : 1;
    const int idx  = isVit ? bid : bid - CRF_B;
    const int half = (idx >> 3) & 1;
    const int sib  = idx ^ 8;
    const int pairIdx = ((idx >> 4) << 3) | (idx & 7);   // 0..63
    const int b0 = 2 * pairIdx, b1 = b0 + 1;
    const int jbase = half * HALF_K;
    const int obase = HALF_K - jbase;                    // sibling half column base
    const int tid = threadIdx.x;
    const int lane = tid & 63, wid = tid >> 6;

    const int L0 = seq_len[b0], L1 = seq_len[b1];
    const int Tmax = max(L0, L1);

    __shared__ __align__(16) float sA[2][CRF_K + 8];
    __shared__ __align__(16) float sP[2][NG][HALF_K + 4];
    __shared__ __align__(16) unsigned short sPB[2][NG][HALF_K + 4];
    __shared__ float sRedA[NWAVE], sRedB[NWAVE];
    __shared__ int   sRedI[NWAVE];
    __shared__ float sB0, sB1;

    const float* pb0 = pot + (size_t)b0 * CRF_T * CRF_K;
    const float* pb1 = pot + (size_t)b1 * CRF_T * CRF_K;

    int* myF  = xflag + role * 128 + idx;
    int* sibF = xflag + role * 128 + sib;

    const bool act = tid < NG * RI;       // 600 workers
    const int g  = tid / RI;              // i-group 0..7
    const int cc = tid % RI;              // 0..74
    const int j0 = jbase + 4 * cc;        // 4 columns per thread
    const int i0 = g * RI;
    const int cp  = tid / HALF_K;         // combine: problem 0/1
    const int cjj = tid % HALF_K;         // combine: column within half

    if (isVit) {
        // ================= Viterbi role =================
        for (int j = tid; j < CRF_K; j += FWD_NT) {
            sA[0][j] = pb0[j];
            sA[1][j] = pb1[j];
        }
        __syncthreads();

        for (int t = 1; t < Tmax; ++t) {
            if (act) {
                float v0=-INFINITY,v1=-INFINITY,v2=-INFINITY,v3=-INFINITY;
                float w0=-INFINITY,w1=-INFINITY,w2=-INFINITY,w3=-INFINITY;
                int ia0=0,ia1=0,ia2=0,ia3=0, ja0=0,ja1=0,ja2=0,ja3=0;
                const float* trow = trans + (size_t)i0 * CRF_K + j0;
                #pragma unroll 5
                for (int ii = 0; ii < RI; ++ii) {
                    float4 tr = *(const float4*)trow; trow += CRF_K;
                    float a0 = sA[0][i0 + ii];
                    float a1 = sA[1][i0 + ii];
                    int ic = i0 + ii;
                    float c;
                    c = a0 + tr.x; if (c > v0) { v0 = c; ia0 = ic; }
                    c = a0 + tr.y; if (c > v1) { v1 = c; ia1 = ic; }
                    c = a0 + tr.z; if (c > v2) { v2 = c; ia2 = ic; }
                    c = a0 + tr.w; if (c > v3) { v3 = c; ia3 = ic; }
                    c = a1 + tr.x; if (c > w0) { w0 = c; ja0 = ic; }
                    c = a1 + tr.y; if (c > w1) { w1 = c; ja1 = ic; }
                    c = a1 + tr.z; if (c > w2) { w2 = c; ja2 = ic; }
                    c = a1 + tr.w; if (c > w3) { w3 = c; ja3 = ic; }
                }
                *(float4*)&sP[0][g][4 * cc] = make_float4(v0, v1, v2, v3);
                *(float4*)&sP[1][g][4 * cc] = make_float4(w0, w1, w2, w3);
                ushort4 u0; u0.x=(unsigned short)ia0; u0.y=(unsigned short)ia1; u0.z=(unsigned short)ia2; u0.w=(unsigned short)ia3;
                ushort4 u1; u1.x=(unsigned short)ja0; u1.y=(unsigned short)ja1; u1.z=(unsigned short)ja2; u1.w=(unsigned short)ja3;
                *(ushort4*)&sPB[0][g][4 * cc] = u0;
                *(ushort4*)&sPB[1][g][4 * cc] = u1;
            }
            __syncthreads();
            if (act) {
                const int j = jbase + cjj;
                float v = sP[cp][0][cjj]; int ix = sPB[cp][0][cjj];
                #pragma unroll
                for (int gg = 1; gg < NG; ++gg) {
                    float vg = sP[cp][gg][cjj];
                    int   ig = sPB[cp][gg][cjj];
                    if (vg > v) { v = vg; ix = ig; }   // groups ascending in i -> first-max
                }
                const int b  = cp ? b1 : b0;
                const int Lp = cp ? L1 : L0;
                const float* pbp = cp ? pb1 : pb0;
                float na;
                if (t < Lp) {
                    bp[((size_t)b * (CRF_T - 1) + (t - 1)) * CRF_K + j] = (unsigned short)ix;
                    na = v + pbp[(size_t)t * CRF_K + j];
                } else {
                    na = sA[cp][j];                    // frozen
                }
                sA[cp][j] = na;
                xbuf[xoff(role, pairIdx, t & 1, half, cp) + cjj] = na;
            }
            __threadfence();
            __syncthreads();
            if (tid == 0) {
                __hip_atomic_store(myF, t, __ATOMIC_RELEASE, __HIP_MEMORY_SCOPE_AGENT);
                while (__hip_atomic_load(sibF, __ATOMIC_ACQUIRE, __HIP_MEMORY_SCOPE_AGENT) < t) {}
            }
            __syncthreads();
            if (act) {
                sA[cp][obase + cjj] = xbuf[xoff(role, pairIdx, t & 1, 1 - half, cp) + cjj];
            }
            __syncthreads();
        }

        // finalize: last = argmax_j sA[p][j] (first-max tie-break); half 0 writes
        for (int p = 0; p < 2; ++p) {
            float mv = (tid < CRF_K) ? sA[p][tid] : -INFINITY;
            float y = mv;
            for (int o = 32; o; o >>= 1) y = fmaxf(y, __shfl_down(y, o));
            if (lane == 0) sRedA[wid] = y;
            __syncthreads();
            if (tid == 0) { float m = sRedA[0]; for (int w = 1; w < NWAVE; ++w) m = fmaxf(m, sRedA[w]); sB0 = m; }
            __syncthreads();
            float vmax = sB0;
            int cand = (tid < CRF_K && mv == vmax) ? tid : 0x7fffffff;
            for (int o = 32; o; o >>= 1) cand = min(cand, __shfl_down(cand, o));
            if (lane == 0) sRedI[wid] = cand;
            __syncthreads();
            if (tid == 0) {
                int mi = sRedI[0];
                for (int w = 1; w < NWAVE; ++w) mi = min(mi, sRedI[w]);
                if (half == 0) lastArr[p ? b1 : b0] = mi;
            }
            __syncthreads();
        }
    } else {
        // ================= lognorm role =================
        float p00 = (tid < CRF_K) ? pb0[tid] : -INFINITY;
        float p01 = (tid < CRF_K) ? pb1[tid] : -INFINITY;
        {
            float y0 = p00, y1 = p01;
            for (int o = 32; o; o >>= 1) { y0 = fmaxf(y0, __shfl_down(y0, o)); y1 = fmaxf(y1, __shfl_down(y1, o)); }
            if (lane == 0) { sRedA[wid] = y0; sRedB[wid] = y1; }
            __syncthreads();
            if (tid == 0) {
                float m0 = sRedA[0], m1 = sRedB[0];
                for (int w = 1; w < NWAVE; ++w) { m0 = fmaxf(m0, sRedA[w]); m1 = fmaxf(m1, sRedB[w]); }
                sB0 = m0; sB1 = m1;
            }
            __syncthreads();
        }
        float ls0 = sB0, ls1 = sB1;    // meaningful on tid 0 only
        if (tid < CRF_K) {
            sA[0][tid] = __expf(p00 - sB0);
            sA[1][tid] = __expf(p01 - sB1);
        }
        __syncthreads();

        for (int t = 1; t < Tmax; ++t) {
            if (act) {
                float s00=0.f,s01=0.f,s02=0.f,s03=0.f;
                float s10=0.f,s11=0.f,s12=0.f,s13=0.f;
                const uint16_t* erow = expT + (size_t)i0 * CRF_K + j0;
                #pragma unroll 5
                for (int ii = 0; ii < RI; ++ii) {
                    uint2 e = *(const uint2*)erow; erow += CRF_K;
                    float e0 = __uint_as_float(e.x << 16);
                    float e1 = __uint_as_float(e.x & 0xffff0000u);
                    float e2 = __uint_as_float(e.y << 16);
                    float e3 = __uint_as_float(e.y & 0xffff0000u);
                    float a0 = sA[0][i0 + ii];
                    float a1 = sA[1][i0 + ii];
                    s00 = fmaf(a0, e0, s00); s01 = fmaf(a0, e1, s01);
                    s02 = fmaf(a0, e2, s02); s03 = fmaf(a0, e3, s03);
                    s10 = fmaf(a1, e0, s10); s11 = fmaf(a1, e1, s11);
                    s12 = fmaf(a1, e2, s12); s13 = fmaf(a1, e3, s13);
                }
                *(float4*)&sP[0][g][4 * cc] = make_float4(s00, s01, s02, s03);
                *(float4*)&sP[1][g][4 * cc] = make_float4(s10, s11, s12, s13);
            }
            __syncthreads();
            if (act) {
                const int j = jbase + cjj;
                float r = sP[cp][0][cjj];
                #pragma unroll
                for (int gg = 1; gg < NG; ++gg) r += sP[cp][gg][cjj];
                const int Lp = cp ? L1 : L0;
                const float* pbp = cp ? pb1 : pb0;
                float na;
                if (t < Lp) na = r * __expf(pbp[(size_t)t * CRF_K + j]);
                else        na = sA[cp][j];
                sA[cp][j] = na;
                xbuf[xoff(role, pairIdx, t & 1, half, cp) + cjj] = na;
            }
            __threadfence();
            __syncthreads();
            if (tid == 0) {
                __hip_atomic_store(myF, t, __ATOMIC_RELEASE, __HIP_MEMORY_SCOPE_AGENT);
                while (__hip_atomic_load(sibF, __ATOMIC_ACQUIRE, __HIP_MEMORY_SCOPE_AGENT) < t) {}
            }
            __syncthreads();
            if (act) {
                sA[cp][obase + cjj] = xbuf[xoff(role, pairIdx, t & 1, 1 - half, cp) + cjj];
            }
            __syncthreads();

            if ((t % RS) == 0) {
                // periodic rescale (both siblings compute identical full-alpha maxes)
                float a0 = (tid < CRF_K) ? sA[0][tid] : 0.f;
                float a1 = (tid < CRF_K) ? sA[1][tid] : 0.f;
                float y0 = a0, y1 = a1;
                for (int o = 32; o; o >>= 1) { y0 = fmaxf(y0, __shfl_down(y0, o)); y1 = fmaxf(y1, __shfl_down(y1, o)); }
                if (lane == 0) { sRedA[wid] = y0; sRedB[wid] = y1; }
                __syncthreads();
                if (tid == 0) {
                    float m0 = sRedA[0], m1 = sRedB[0];
                    for (int w = 1; w < NWAVE; ++w) { m0 = fmaxf(m0, sRedA[w]); m1 = fmaxf(m1, sRedB[w]); }
                    sB0 = m0; sB1 = m1;
                }
                __syncthreads();
                float i0v = 1.0f / sB0, i1v = 1.0f / sB1;
                if (tid == 0) { ls0 += __logf(sB0); ls1 += __logf(sB1); }
                if (tid < CRF_K) { sA[0][tid] *= i0v; sA[1][tid] *= i1v; }
                __syncthreads();
            }
        }

        // finalize lognorm = logscale + log(sum alpha)
        float a0 = (tid < CRF_K) ? sA[0][tid] : 0.f;
        float a1 = (tid < CRF_K) ? sA[1][tid] : 0.f;
        for (int o = 32; o; o >>= 1) { a0 += __shfl_down(a0, o); a1 += __shfl_down(a1, o); }
        if (lane == 0) { sRedA[wid] = a0; sRedB[wid] = a1; }
        __syncthreads();
        if (tid == 0 && half == 0) {
            float S0 = 0.f, S1 = 0.f;
            for (int w = 0; w < NWAVE; ++w) { S0 += sRedA[w]; S1 += sRedB[w]; }
            lognormArr[b0] = ls0 + __logf(S0);
            lognormArr[b1] = ls1 + __logf(S1);
        }
    }
}

// ---------------- backtrace ----------------
__global__ __launch_bounds__(64) void backtrace_kernel(const uint16_t* __restrict__ bp,
                                                       const int* __restrict__ seq_len,
                                                       const int* __restrict__ lastArr,
                                                       float* __restrict__ out)
{
    int r = blockIdx.x * 64 + threadIdx.x;
    if (r >= CRF_B) return;
    int L = seq_len[r];
    float* o = out + 1 + (size_t)r * CRF_T;
    int tag = lastArr[r];
    for (int t = CRF_T - 1; t >= L; --t) o[t] = 0.f;
    o[L - 1] = (float)tag;
    for (int t = L - 2; t >= 0; --t) {
        tag = bp[((size_t)r * (CRF_T - 1) + t) * CRF_K + tag];
        o[t] = (float)tag;
    }
}

// ---------------- loss = -mean(score - lognorm) ----------------
__global__ __launch_bounds__(128) void loss_kernel(const float* __restrict__ scoreArr,
                                                   const float* __restrict__ lognormArr,
                                                   float* __restrict__ out)
{
    int tid = threadIdx.x;
    float x = scoreArr[tid] - lognormArr[tid];
    for (int o = 32; o; o >>= 1) x += __shfl_down(x, o);
    __shared__ float r2[2];
    if ((tid & 63) == 0) r2[tid >> 6] = x;
    __syncthreads();
    if (tid == 0) out[0] = -(r2[0] + r2[1]) / (float)CRF_B;
}

extern "C" void kernel_launch(void* const* d_in, const int* in_sizes, int n_in,
                              void* d_out, int out_size, void* d_ws, size_t ws_size,
                              hipStream_t stream)
{
    const float* pot     = (const float*)d_in[0];
    const float* trans   = (const float*)d_in[1];
    const int*   tags    = (const int*)d_in[2];
    const int*   seq_len = (const int*)d_in[3];
    float* out = (float*)d_out;

    char* ws = (char*)d_ws;
    const size_t bpBytes   = (size_t)CRF_B * (CRF_T - 1) * CRF_K * 2;   // 39,168,000
    const size_t expTBytes = (size_t)CRF_K * CRF_K * 2;                 //    720,000
    const size_t xbufBytes = (size_t)2 * 64 * 2 * 2 * 2 * HALF_K * 4;   //  1,228,800
    uint16_t* bp    = (uint16_t*)ws;
    uint16_t* expT  = (uint16_t*)(ws + bpBytes);
    float*    xbuf  = (float*)(ws + bpBytes + expTBytes);
    int*      xflag = (int*)(ws + bpBytes + expTBytes + xbufBytes);
    float* scoreArr   = (float*)(xflag + 256);
    float* lognormArr = scoreArr + CRF_B;
    int*   lastArr    = (int*)(lognormArr + CRF_B);

    prep_kernel<<<(CRF_K * CRF_K + 255) / 256, 256, 0, stream>>>(trans, expT, xflag);
    score_kernel<<<CRF_B, 64, 0, stream>>>(pot, trans, tags, seq_len, scoreArr);
    fwd_kernel<<<2 * CRF_B, FWD_NT, 0, stream>>>(pot, trans, expT, seq_len, bp,
                                                 lognormArr, lastArr, xbuf, xflag);
    backtrace_kernel<<<(CRF_B + 63) / 64, 64, 0, stream>>>(bp, seq_len, lastArr, out);
    loss_kernel<<<1, 128, 0, stream>>>(scoreArr, lognormArr, out);
}

// Round 5
// 2407.777 us; speedup vs baseline: 5.6128x; 5.6128x over previous
//
#include <hip/hip_runtime.h>
#include <stdint.h>

#define CRF_B 128
#define CRF_T 256
#define CRF_K 600
#define FWD_NT 640          // 10 waves
#define NWAVE 10
#define RS 4                // lognorm rescale interval (power of 2)
#define RIL 75              // lognorm rows per i-group (8 groups x 75 = 600)

// ---------------- prep: expT[i,j] = bf16(exp(trans[i,j])) ----------------
__global__ __launch_bounds__(256) void prep_kernel(const float* __restrict__ trans,
                                                   uint16_t* __restrict__ expT)
{
    int idx = blockIdx.x * 256 + threadIdx.x;
    if (idx < CRF_K * CRF_K) {
        float e = __expf(trans[idx]);
        uint32_t u = __float_as_uint(e);
        u += 0x7fffu + ((u >> 16) & 1u);   // RNE to bf16
        expT[idx] = (uint16_t)(u >> 16);
    }
}

// ---------------- prep2: per-row max/min of trans ----------------
__global__ __launch_bounds__(64) void prep2_kernel(const float* __restrict__ trans,
                                                   float* __restrict__ rowmax,
                                                   float* __restrict__ rowmin)
{
    int r = blockIdx.x;
    int lane = threadIdx.x;
    float mx = -INFINITY, mn = INFINITY;
    for (int j = lane; j < CRF_K; j += 64) {
        float v = trans[r * CRF_K + j];
        mx = fmaxf(mx, v);
        mn = fminf(mn, v);
    }
    for (int o = 32; o; o >>= 1) {
        mx = fmaxf(mx, __shfl_down(mx, o));
        mn = fminf(mn, __shfl_down(mn, o));
    }
    if (lane == 0) { rowmax[r] = mx; rowmin[r] = mn; }
}

// ---------------- gold-path score: unary + binary ----------------
__global__ __launch_bounds__(64) void score_kernel(const float* __restrict__ pot,
                                                   const float* __restrict__ trans,
                                                   const int* __restrict__ tags,
                                                   const int* __restrict__ seq_len,
                                                   float* __restrict__ scoreArr)
{
    int b = blockIdx.x;
    int lane = threadIdx.x;
    int L = seq_len[b];
    float s = 0.f;
    for (int t = lane; t < CRF_T; t += 64) {
        if (t < L) {
            int tg = tags[b * CRF_T + t];
            s += pot[((size_t)b * CRF_T + t) * CRF_K + tg];
            if (t >= 1) {
                int tp = tags[b * CRF_T + t - 1];
                s += trans[tp * CRF_K + tg];
            }
        }
    }
    for (int o = 32; o; o >>= 1) s += __shfl_down(s, o);
    if (lane == 0) scoreArr[b] = s;
}

// ---------------- fused forward ----------------
// blocks 0..127   : Viterbi, 1 row/block, exact pruned max-plus
// blocks 128..191 : lognorm, 2 rows/block, bf16 expT, periodic rescale
__global__ __launch_bounds__(FWD_NT) void fwd_kernel(
    const float* __restrict__ pot,
    const float* __restrict__ trans,
    const uint16_t* __restrict__ expT,
    const float* __restrict__ rowmax,
    const float* __restrict__ rowmin,
    const int* __restrict__ seq_len,
    uint16_t* __restrict__ bp,
    float* __restrict__ lognormArr,
    int* __restrict__ lastArr)
{
    const int bid = blockIdx.x;
    const int tid = threadIdx.x;
    const int lane = tid & 63, wid = tid >> 6;
    const bool act = tid < CRF_K;

    __shared__ __align__(16) float sAv[2][CRF_K];        // viterbi alpha dbuf
    __shared__ int   sCand[CRF_K];
    __shared__ __align__(16) float sAl[2][2][CRF_K];     // lognorm alpha dbuf [buf][p][j]
    __shared__ __align__(16) float sP[2][8][RIL * 8 + 8];// lognorm partials [p][g][col]
    __shared__ float sRedA[NWAVE], sRedB[NWAVE];
    __shared__ int   sRedI[NWAVE];
    __shared__ float sB0f, sB1f;

    if (bid < CRF_B) {
        // ================= Viterbi role =================
        const int b = bid;
        const int L = seq_len[b];
        const float* pb = pot + (size_t)b * CRF_T * CRF_K;
        float rmx = act ? rowmax[tid] : 0.f;
        float rmn = act ? rowmin[tid] : 0.f;
        if (act) sAv[0][tid] = pb[tid];
        int cur = 0;
        __syncthreads();

        for (int t = 1; t < L; ++t) {
            float a_own = act ? sAv[cur][tid] : -INFINITY;
            // LB = max_i (alpha_i + rowmin_i)
            float li = act ? a_own + rmn : -INFINITY;
            for (int o = 32; o; o >>= 1) li = fmaxf(li, __shfl_down(li, o));
            if (lane == 0) sRedA[wid] = li;
            __syncthreads();                                   // B1
            if (tid == 0) { float m = sRedA[0]; for (int w = 1; w < NWAVE; ++w) m = fmaxf(m, sRedA[w]); sB0f = m; }
            __syncthreads();                                   // B2
            const float LB = sB0f;
            // candidate set: alpha_i + rowmax_i >= LB  (superset of all winners/tiers)
            bool flag = act && (a_own + rmx >= LB);
            uint64_t mask = __ballot(flag);
            if (lane == 0) sRedI[wid] = __popcll(mask);
            __syncthreads();                                   // B3
            int woff = 0, NC = 0;
            for (int w = 0; w < NWAVE; ++w) { int c0 = sRedI[w]; if (w < wid) woff += c0; NC += c0; }
            if (flag) sCand[woff + __popcll(mask & ((1ull << lane) - 1ull))] = tid;
            __syncthreads();                                   // B4
            if (act) {
                float v = -INFINITY; int ix = 0;
                for (int k0 = 0; k0 < NC; k0 += 8) {
                    #pragma unroll
                    for (int u = 0; u < 8; ++u) {
                        int kk = k0 + u;
                        int i = sCand[(kk < NC) ? kk : 0];     // dup-pad tail (no effect on lex-min)
                        float cnd = sAv[cur][i] + trans[i * CRF_K + tid];
                        if (cnd > v || (cnd == v && i < ix)) { v = cnd; ix = i; }
                    }
                }
                bp[((size_t)b * (CRF_T - 1) + (t - 1)) * CRF_K + tid] = (uint16_t)ix;
                sAv[cur ^ 1][tid] = v + pb[(size_t)t * CRF_K + tid];
            }
            cur ^= 1;
            // no trailing barrier: next iter's B1..B4 precede any cross-thread sAv/sCand access
        }

        // finalize: last = argmax_j alpha (first-max tie-break)
        float mv = act ? sAv[cur][tid] : -INFINITY;
        float y = mv;
        for (int o = 32; o; o >>= 1) y = fmaxf(y, __shfl_down(y, o));
        if (lane == 0) sRedA[wid] = y;
        __syncthreads();
        if (tid == 0) { float m = sRedA[0]; for (int w = 1; w < NWAVE; ++w) m = fmaxf(m, sRedA[w]); sB0f = m; }
        __syncthreads();
        float vmax = sB0f;
        int cand = (act && mv == vmax) ? tid : 0x7fffffff;
        for (int o = 32; o; o >>= 1) cand = min(cand, __shfl_down(cand, o));
        if (lane == 0) sRedI[wid] = cand;
        __syncthreads();
        if (tid == 0) {
            int mi = sRedI[0];
            for (int w = 1; w < NWAVE; ++w) mi = min(mi, sRedI[w]);
            lastArr[b] = mi;
        }
    } else {
        // ================= lognorm role (NB=2) =================
        const int q = bid - CRF_B;
        const int b0 = 2 * q, b1 = b0 + 1;
        const int L0 = seq_len[b0], L1 = seq_len[b1];
        const int Tmax = max(L0, L1);
        const float* pb0 = pot + (size_t)b0 * CRF_T * CRF_K;
        const float* pb1 = pot + (size_t)b1 * CRF_T * CRF_K;
        const int g = tid / RIL;          // i-group 0..7 (act threads)
        const int cc = tid % RIL;
        const int j0 = 8 * cc;            // 8 cols per thread
        const int i0 = g * RIL;

        // init
        float p00 = act ? pb0[tid] : -INFINITY;
        float p01 = act ? pb1[tid] : -INFINITY;
        {
            float y0 = p00, y1 = p01;
            for (int o = 32; o; o >>= 1) { y0 = fmaxf(y0, __shfl_down(y0, o)); y1 = fmaxf(y1, __shfl_down(y1, o)); }
            if (lane == 0) { sRedA[wid] = y0; sRedB[wid] = y1; }
            __syncthreads();
            if (tid == 0) {
                float m0 = sRedA[0], m1 = sRedB[0];
                for (int w = 1; w < NWAVE; ++w) { m0 = fmaxf(m0, sRedA[w]); m1 = fmaxf(m1, sRedB[w]); }
                sB0f = m0; sB1f = m1;
            }
            __syncthreads();
        }
        float ls0 = sB0f, ls1 = sB1f;     // meaningful on tid 0 only
        if (act) {
            sAl[0][0][tid] = __expf(p00 - sB0f);
            sAl[0][1][tid] = __expf(p01 - sB1f);
        }
        int cur = 0;
        __syncthreads();

        for (int t = 1; t < Tmax; ++t) {
            if (act) {
                float s00=0.f,s01=0.f,s02=0.f,s03=0.f,s04=0.f,s05=0.f,s06=0.f,s07=0.f;
                float s10=0.f,s11=0.f,s12=0.f,s13=0.f,s14=0.f,s15=0.f,s16=0.f,s17=0.f;
                const uint16_t* erow = expT + (size_t)i0 * CRF_K + j0;
                const float* a0p = &sAl[cur][0][i0];
                const float* a1p = &sAl[cur][1][i0];
                #pragma unroll 5
                for (int ii = 0; ii < RIL; ++ii) {
                    uint4 e = *(const uint4*)erow; erow += CRF_K;
                    float a0 = a0p[ii], a1 = a1p[ii];
                    float e0 = __uint_as_float(e.x << 16), e1 = __uint_as_float(e.x & 0xffff0000u);
                    float e2 = __uint_as_float(e.y << 16), e3 = __uint_as_float(e.y & 0xffff0000u);
                    float e4 = __uint_as_float(e.z << 16), e5 = __uint_as_float(e.z & 0xffff0000u);
                    float e6 = __uint_as_float(e.w << 16), e7 = __uint_as_float(e.w & 0xffff0000u);
                    s00 = fmaf(a0, e0, s00); s01 = fmaf(a0, e1, s01);
                    s02 = fmaf(a0, e2, s02); s03 = fmaf(a0, e3, s03);
                    s04 = fmaf(a0, e4, s04); s05 = fmaf(a0, e5, s05);
                    s06 = fmaf(a0, e6, s06); s07 = fmaf(a0, e7, s07);
                    s10 = fmaf(a1, e0, s10); s11 = fmaf(a1, e1, s11);
                    s12 = fmaf(a1, e2, s12); s13 = fmaf(a1, e3, s13);
                    s14 = fmaf(a1, e4, s14); s15 = fmaf(a1, e5, s15);
                    s16 = fmaf(a1, e6, s16); s17 = fmaf(a1, e7, s17);
                }
                *(float4*)&sP[0][g][j0]     = make_float4(s00, s01, s02, s03);
                *(float4*)&sP[0][g][j0 + 4] = make_float4(s04, s05, s06, s07);
                *(float4*)&sP[1][g][j0]     = make_float4(s10, s11, s12, s13);
                *(float4*)&sP[1][g][j0 + 4] = make_float4(s14, s15, s16, s17);
            }
            __syncthreads();                                   // B1
            // combine: 1200 jobs over 640 threads
            float mx0 = 0.f, mx1 = 0.f;
            {
                int job = tid;
                #pragma unroll
                for (int itj = 0; itj < 2; ++itj, job += FWD_NT) {
                    if (job < 2 * CRF_K) {
                        int p = (job >= CRF_K) ? 1 : 0;
                        int col = job - p * CRF_K;
                        float r = ((sP[p][0][col] + sP[p][1][col]) + (sP[p][2][col] + sP[p][3][col]))
                                + ((sP[p][4][col] + sP[p][5][col]) + (sP[p][6][col] + sP[p][7][col]));
                        const float* pbp = p ? pb1 : pb0;
                        const int Lp = p ? L1 : L0;
                        float na = (t < Lp) ? r * __expf(pbp[(size_t)t * CRF_K + col])
                                            : sAl[cur][p][col];          // frozen (own value)
                        sAl[cur ^ 1][p][col] = na;
                        if (p) mx1 = fmaxf(mx1, na); else mx0 = fmaxf(mx0, na);
                    }
                }
            }
            if ((t & (RS - 1)) == 0) {
                // periodic rescale: lognorm = ls + log(sum alpha) invariant under uniform rescale
                for (int o = 32; o; o >>= 1) { mx0 = fmaxf(mx0, __shfl_down(mx0, o)); mx1 = fmaxf(mx1, __shfl_down(mx1, o)); }
                if (lane == 0) { sRedA[wid] = mx0; sRedB[wid] = mx1; }
                __syncthreads();                               // B2a
                if (tid == 0) {
                    float m0 = sRedA[0], m1 = sRedB[0];
                    for (int w = 1; w < NWAVE; ++w) { m0 = fmaxf(m0, sRedA[w]); m1 = fmaxf(m1, sRedB[w]); }
                    sB0f = m0; sB1f = m1;
                    ls0 += __logf(m0); ls1 += __logf(m1);
                }
                __syncthreads();                               // B2b
                float i0v = 1.0f / sB0f, i1v = 1.0f / sB1f;
                int job = tid;
                #pragma unroll
                for (int itj = 0; itj < 2; ++itj, job += FWD_NT) {
                    if (job < 2 * CRF_K) {
                        int p = (job >= CRF_K) ? 1 : 0;
                        int col = job - p * CRF_K;
                        sAl[cur ^ 1][p][col] *= (p ? i1v : i0v);   // same thread as writer: no hazard
                    }
                }
                __syncthreads();                               // B3
            } else {
                __syncthreads();                               // B2
            }
            cur ^= 1;
        }

        // finalize: lognorm = ls + log(sum alpha)
        float a0s = act ? sAl[cur][0][tid] : 0.f;
        float a1s = act ? sAl[cur][1][tid] : 0.f;
        for (int o = 32; o; o >>= 1) { a0s += __shfl_down(a0s, o); a1s += __shfl_down(a1s, o); }
        if (lane == 0) { sRedA[wid] = a0s; sRedB[wid] = a1s; }
        __syncthreads();
        if (tid == 0) {
            float S0 = 0.f, S1 = 0.f;
            for (int w = 0; w < NWAVE; ++w) { S0 += sRedA[w]; S1 += sRedB[w]; }
            lognormArr[b0] = ls0 + __logf(S0);
            lognormArr[b1] = ls1 + __logf(S1);
        }
    }
}

// ---------------- backtrace ----------------
__global__ __launch_bounds__(64) void backtrace_kernel(const uint16_t* __restrict__ bp,
                                                       const int* __restrict__ seq_len,
                                                       const int* __restrict__ lastArr,
                                                       float* __restrict__ out)
{
    int r = blockIdx.x * 64 + threadIdx.x;
    if (r >= CRF_B) return;
    int L = seq_len[r];
    float* o = out + 1 + (size_t)r * CRF_T;
    int tag = lastArr[r];
    for (int t = CRF_T - 1; t >= L; --t) o[t] = 0.f;
    o[L - 1] = (float)tag;
    for (int t = L - 2; t >= 0; --t) {
        tag = bp[((size_t)r * (CRF_T - 1) + t) * CRF_K + tag];
        o[t] = (float)tag;
    }
}

// ---------------- loss = -mean(score - lognorm) ----------------
__global__ __launch_bounds__(128) void loss_kernel(const float* __restrict__ scoreArr,
                                                   const float* __restrict__ lognormArr,
                                                   float* __restrict__ out)
{
    int tid = threadIdx.x;
    float x = scoreArr[tid] - lognormArr[tid];
    for (int o = 32; o; o >>= 1) x += __shfl_down(x, o);
    __shared__ float r2[2];
    if ((tid & 63) == 0) r2[tid >> 6] = x;
    __syncthreads();
    if (tid == 0) out[0] = -(r2[0] + r2[1]) / (float)CRF_B;
}

extern "C" void kernel_launch(void* const* d_in, const int* in_sizes, int n_in,
                              void* d_out, int out_size, void* d_ws, size_t ws_size,
                              hipStream_t stream)
{
    const float* pot     = (const float*)d_in[0];
    const float* trans   = (const float*)d_in[1];
    const int*   tags    = (const int*)d_in[2];
    const int*   seq_len = (const int*)d_in[3];
    float* out = (float*)d_out;

    char* ws = (char*)d_ws;
    const size_t bpBytes   = (size_t)CRF_B * (CRF_T - 1) * CRF_K * 2;   // 39,168,000
    const size_t expTBytes = (size_t)CRF_K * CRF_K * 2;                 //    720,000
    uint16_t* bp     = (uint16_t*)ws;
    uint16_t* expT   = (uint16_t*)(ws + bpBytes);
    float*    rowmax = (float*)(ws + bpBytes + expTBytes);
    float*    rowmin = rowmax + CRF_K;
    float* scoreArr   = rowmin + CRF_K;
    float* lognormArr = scoreArr + CRF_B;
    int*   lastArr    = (int*)(lognormArr + CRF_B);

    prep_kernel<<<(CRF_K * CRF_K + 255) / 256, 256, 0, stream>>>(trans, expT);
    prep2_kernel<<<CRF_K, 64, 0, stream>>>(trans, rowmax, rowmin);
    score_kernel<<<CRF_B, 64, 0, stream>>>(pot, trans, tags, seq_len, scoreArr);
    fwd_kernel<<<CRF_B + CRF_B / 2, FWD_NT, 0, stream>>>(pot, trans, expT, rowmax, rowmin,
                                                         seq_len, bp, lognormArr, lastArr);
    backtrace_kernel<<<(CRF_B + 63) / 64, 64, 0, stream>>>(bp, seq_len, lastArr, out);
    loss_kernel<<<1, 128, 0, stream>>>(scoreArr, lognormArr, out);
}

// Round 6
// 1649.578 us; speedup vs baseline: 8.1927x; 1.4596x over previous
//
#include <hip/hip_runtime.h>
#include <stdint.h>

#define CRF_B 128
#define CRF_T 256
#define CRF_K 600
#define FWD_NT 640          // 10 waves
#define NWAVE 10
#define RS 4                // lognorm rescale interval (power of 2)
#define RIL 75              // rows per i-group (8 groups x 75 = 600)
#define PS 608              // sP row stride (floats)

typedef float v2f __attribute__((ext_vector_type(2)));

// ---------------- prep: expT8[i,j] = fp8_e4m3(exp(trans[i,j])), 4 elems/word ----------------
__global__ __launch_bounds__(256) void prep_kernel(const float* __restrict__ trans,
                                                   uint32_t* __restrict__ expT8)
{
    int q = blockIdx.x * 256 + threadIdx.x;            // one 4-element group
    if (q < CRF_K * CRF_K / 4) {
        float4 v = *(const float4*)(trans + 4 * q);
        float e0 = __expf(v.x), e1 = __expf(v.y), e2 = __expf(v.z), e3 = __expf(v.w);
        int u = __builtin_amdgcn_cvt_pk_fp8_f32(e0, e1, 0, false);
        u     = __builtin_amdgcn_cvt_pk_fp8_f32(e2, e3, u, true);
        expT8[q] = (uint32_t)u;
    }
}

// ---------------- prep2: per-row max/min of trans ----------------
__global__ __launch_bounds__(64) void prep2_kernel(const float* __restrict__ trans,
                                                   float* __restrict__ rowmax,
                                                   float* __restrict__ rowmin)
{
    int r = blockIdx.x;
    int lane = threadIdx.x;
    float mx = -INFINITY, mn = INFINITY;
    for (int j = lane; j < CRF_K; j += 64) {
        float v = trans[r * CRF_K + j];
        mx = fmaxf(mx, v);
        mn = fminf(mn, v);
    }
    for (int o = 32; o; o >>= 1) {
        mx = fmaxf(mx, __shfl_down(mx, o));
        mn = fminf(mn, __shfl_down(mn, o));
    }
    if (lane == 0) { rowmax[r] = mx; rowmin[r] = mn; }
}

// ---------------- gold-path score: unary + binary ----------------
__global__ __launch_bounds__(64) void score_kernel(const float* __restrict__ pot,
                                                   const float* __restrict__ trans,
                                                   const int* __restrict__ tags,
                                                   const int* __restrict__ seq_len,
                                                   float* __restrict__ scoreArr)
{
    int b = blockIdx.x;
    int lane = threadIdx.x;
    int L = seq_len[b];
    float s = 0.f;
    for (int t = lane; t < CRF_T; t += 64) {
        if (t < L) {
            int tg = tags[b * CRF_T + t];
            s += pot[((size_t)b * CRF_T + t) * CRF_K + tg];
            if (t >= 1) {
                int tp = tags[b * CRF_T + t - 1];
                s += trans[tp * CRF_K + tg];
            }
        }
    }
    for (int o = 32; o; o >>= 1) s += __shfl_down(s, o);
    if (lane == 0) scoreArr[b] = s;
}

// ---------------- fused forward ----------------
// blocks 0..127   : Viterbi, 1 row/block, exact pruned max-plus (bit-exact f32)
// blocks 128..255 : lognorm, 1 row/block, fp8 expT, periodic rescale
// 60KB dynamic-LDS pad forces 1 block/CU (static ~32KB + 60KB > 80KB).
__global__ __launch_bounds__(FWD_NT) void fwd_kernel(
    const float* __restrict__ pot,
    const float* __restrict__ trans,
    const uint32_t* __restrict__ expT8,
    const float* __restrict__ rowmax,
    const float* __restrict__ rowmin,
    const int* __restrict__ seq_len,
    uint16_t* __restrict__ bp,
    float* __restrict__ lognormArr,
    int* __restrict__ lastArr)
{
    extern __shared__ char dynpad[];
    const int bid = blockIdx.x;
    const int tid = threadIdx.x;
    const int lane = tid & 63, wid = tid >> 6;
    const bool act = tid < CRF_K;

    __shared__ __align__(16) float sAv[2][CRF_K];   // viterbi alpha dbuf
    __shared__ int   sCand[FWD_NT];                 // per-wave candidate lists (64 slots/wave)
    __shared__ __align__(16) float sAl[2][CRF_K];   // lognorm alpha dbuf
    __shared__ __align__(16) float sP[8][PS];       // lognorm partials, swizzled [g][k*75+cc]
    __shared__ float sRedA[NWAVE];
    __shared__ int   sRedI[NWAVE];
    __shared__ float sB0f;

    if (bid < CRF_B) {
        // ================= Viterbi role =================
        const int b = bid;
        const int L = seq_len[b];
        if (L < 0) ((volatile char*)dynpad)[0] = 1;   // keep dynpad allocated (never true)
        const float* pb = pot + (size_t)b * CRF_T * CRF_K;
        float rmx = act ? rowmax[tid] : 0.f;
        float rmn = act ? rowmin[tid] : 0.f;
        if (act) sAv[0][tid] = pb[tid];
        int cur = 0;
        __syncthreads();

        for (int t = 1; t < L; ++t) {
            float a_own = act ? sAv[cur][tid] : -INFINITY;
            // LB = max_i (alpha_i + rowmin_i)
            float li = act ? a_own + rmn : -INFINITY;
            for (int o = 32; o; o >>= 1) li = fmaxf(li, __shfl_down(li, o));
            if (lane == 0) sRedA[wid] = li;
            __syncthreads();                               // B1
            if (wid == 0) {
                float m = (lane < NWAVE) ? sRedA[lane] : -INFINITY;
                for (int o = 8; o; o >>= 1) m = fmaxf(m, __shfl_down(m, o));
                if (lane == 0) sB0f = m;
            }
            __syncthreads();                               // B2
            const float LB = sB0f;
            // candidates: alpha_i + rowmax_i >= LB (superset of all winners incl. ties)
            bool flag = act && (a_own + rmx >= LB);
            uint64_t mask = __ballot(flag);
            if (flag) sCand[(wid << 6) + __popcll(mask & ((1ull << lane) - 1ull))] = tid;
            if (lane == 0) sRedI[wid] = __popcll(mask);
            __syncthreads();                               // B3
            if (act) {
                float v = -INFINITY; int ix = 0;
                #pragma unroll 2
                for (int w = 0; w < NWAVE; ++w) {
                    const int cw = sRedI[w];
                    const int base = w << 6;
                    for (int k0 = 0; k0 < cw; k0 += 4) {
                        #pragma unroll
                        for (int u = 0; u < 4; ++u) {
                            int kk = k0 + u;
                            int i = sCand[base + ((kk < cw) ? kk : 0)];  // dup-pad: earlier i, strict > no-op
                            float cnd = sAv[cur][i] + trans[i * CRF_K + tid];
                            if (cnd > v) { v = cnd; ix = i; }            // ascending i -> first-max
                        }
                    }
                }
                bp[((size_t)b * (CRF_T - 1) + (t - 1)) * CRF_K + tid] = (uint16_t)ix;
                sAv[cur ^ 1][tid] = v + pb[(size_t)t * CRF_K + tid];
            }
            cur ^= 1;
        }

        // finalize: last = argmax_j alpha (first-max tie-break)
        float mv = act ? sAv[cur][tid] : -INFINITY;
        float y = mv;
        for (int o = 32; o; o >>= 1) y = fmaxf(y, __shfl_down(y, o));
        if (lane == 0) sRedA[wid] = y;
        __syncthreads();
        if (tid == 0) { float m = sRedA[0]; for (int w = 1; w < NWAVE; ++w) m = fmaxf(m, sRedA[w]); sB0f = m; }
        __syncthreads();
        float vmax = sB0f;
        int cand = (act && mv == vmax) ? tid : 0x7fffffff;
        for (int o = 32; o; o >>= 1) cand = min(cand, __shfl_down(cand, o));
        if (lane == 0) sRedI[wid] = cand;
        __syncthreads();
        if (tid == 0) {
            int mi = sRedI[0];
            for (int w = 1; w < NWAVE; ++w) mi = min(mi, sRedI[w]);
            lastArr[b] = mi;
        }
    } else {
        // ================= lognorm role (1 row/block, fp8 E) =================
        const int b = bid - CRF_B;
        const int L = seq_len[b];
        if (L < 0) ((volatile char*)dynpad)[0] = 1;
        const float* pb = pot + (size_t)b * CRF_T * CRF_K;
        const int g  = tid / RIL;         // i-group 0..7 (act threads)
        const int cc = tid % RIL;         // 0..74
        const int i0 = g * RIL;
        const int wbase = i0 * (CRF_K / 4) + 2 * cc;   // word index of [i0][8cc]

        // init
        float p0 = act ? pb[tid] : -INFINITY;
        {
            float y = p0;
            for (int o = 32; o; o >>= 1) y = fmaxf(y, __shfl_down(y, o));
            if (lane == 0) sRedA[wid] = y;
            __syncthreads();
            if (tid == 0) { float m = sRedA[0]; for (int w = 1; w < NWAVE; ++w) m = fmaxf(m, sRedA[w]); sB0f = m; }
            __syncthreads();
        }
        float ls = sB0f;                  // meaningful on tid 0 only
        if (act) sAl[0][tid] = __expf(p0 - sB0f);
        int cur = 0;
        __syncthreads();

        for (int t = 1; t < L; ++t) {
            if (act) {
                float s0=0.f,s1=0.f,s2=0.f,s3=0.f,s4=0.f,s5=0.f,s6=0.f,s7=0.f;
                const uint32_t* erow = expT8 + wbase;
                const float* ap = &sAl[cur][i0];
                #pragma unroll 5
                for (int ii = 0; ii < RIL; ++ii) {
                    uint2 e = *(const uint2*)erow; erow += CRF_K / 4;
                    float av = ap[ii];
                    v2f f01 = __builtin_amdgcn_cvt_pk_f32_fp8((int)e.x, false);
                    v2f f23 = __builtin_amdgcn_cvt_pk_f32_fp8((int)e.x, true);
                    v2f f45 = __builtin_amdgcn_cvt_pk_f32_fp8((int)e.y, false);
                    v2f f67 = __builtin_amdgcn_cvt_pk_f32_fp8((int)e.y, true);
                    s0 = fmaf(av, f01.x, s0); s1 = fmaf(av, f01.y, s1);
                    s2 = fmaf(av, f23.x, s2); s3 = fmaf(av, f23.y, s3);
                    s4 = fmaf(av, f45.x, s4); s5 = fmaf(av, f45.y, s5);
                    s6 = fmaf(av, f67.x, s6); s7 = fmaf(av, f67.y, s7);
                }
                // swizzled stores: [g][k*75+cc] -> stride-1 across lanes, conflict-free
                sP[g][0*RIL+cc]=s0; sP[g][1*RIL+cc]=s1; sP[g][2*RIL+cc]=s2; sP[g][3*RIL+cc]=s3;
                sP[g][4*RIL+cc]=s4; sP[g][5*RIL+cc]=s5; sP[g][6*RIL+cc]=s6; sP[g][7*RIL+cc]=s7;
            }
            __syncthreads();                               // B1
            float mx = 0.f;
            if (act) {
                const int off = (tid & 7) * RIL + (tid >> 3);   // partial slot of column tid
                float r = ((sP[0][off] + sP[1][off]) + (sP[2][off] + sP[3][off]))
                        + ((sP[4][off] + sP[5][off]) + (sP[6][off] + sP[7][off]));
                float na = r * __expf(pb[(size_t)t * CRF_K + tid]);
                sAl[cur ^ 1][tid] = na;
                mx = na;
            }
            if ((t & (RS - 1)) == 0) {
                // periodic rescale: lognorm = ls + log(sum alpha) invariant
                for (int o = 32; o; o >>= 1) mx = fmaxf(mx, __shfl_down(mx, o));
                if (lane == 0) sRedA[wid] = mx;
                __syncthreads();                           // B2a
                if (tid == 0) {
                    float m = sRedA[0];
                    for (int w = 1; w < NWAVE; ++w) m = fmaxf(m, sRedA[w]);
                    sB0f = m; ls += __logf(m);
                }
                __syncthreads();                           // B2b
                float iv = 1.0f / sB0f;
                if (act) sAl[cur ^ 1][tid] *= iv;          // same thread as writer
                __syncthreads();                           // B3
            } else {
                __syncthreads();                           // B2
            }
            cur ^= 1;
        }

        // finalize: lognorm = ls + log(sum alpha)
        float a0s = act ? sAl[cur][tid] : 0.f;
        for (int o = 32; o; o >>= 1) a0s += __shfl_down(a0s, o);
        if (lane == 0) sRedA[wid] = a0s;
        __syncthreads();
        if (tid == 0) {
            float S = 0.f;
            for (int w = 0; w < NWAVE; ++w) S += sRedA[w];
            lognormArr[b] = ls + __logf(S);
        }
    }
}

// ---------------- backtrace ----------------
__global__ __launch_bounds__(64) void backtrace_kernel(const uint16_t* __restrict__ bp,
                                                       const int* __restrict__ seq_len,
                                                       const int* __restrict__ lastArr,
                                                       float* __restrict__ out)
{
    int r = blockIdx.x * 64 + threadIdx.x;
    if (r >= CRF_B) return;
    int L = seq_len[r];
    float* o = out + 1 + (size_t)r * CRF_T;
    int tag = lastArr[r];
    for (int t = CRF_T - 1; t >= L; --t) o[t] = 0.f;
    o[L - 1] = (float)tag;
    for (int t = L - 2; t >= 0; --t) {
        tag = bp[((size_t)r * (CRF_T - 1) + t) * CRF_K + tag];
        o[t] = (float)tag;
    }
}

// ---------------- loss = -mean(score - lognorm) ----------------
__global__ __launch_bounds__(128) void loss_kernel(const float* __restrict__ scoreArr,
                                                   const float* __restrict__ lognormArr,
                                                   float* __restrict__ out)
{
    int tid = threadIdx.x;
    float x = scoreArr[tid] - lognormArr[tid];
    for (int o = 32; o; o >>= 1) x += __shfl_down(x, o);
    __shared__ float r2[2];
    if ((tid & 63) == 0) r2[tid >> 6] = x;
    __syncthreads();
    if (tid == 0) out[0] = -(r2[0] + r2[1]) / (float)CRF_B;
}

extern "C" void kernel_launch(void* const* d_in, const int* in_sizes, int n_in,
                              void* d_out, int out_size, void* d_ws, size_t ws_size,
                              hipStream_t stream)
{
    const float* pot     = (const float*)d_in[0];
    const float* trans   = (const float*)d_in[1];
    const int*   tags    = (const int*)d_in[2];
    const int*   seq_len = (const int*)d_in[3];
    float* out = (float*)d_out;

    char* ws = (char*)d_ws;
    const size_t bpBytes   = (size_t)CRF_B * (CRF_T - 1) * CRF_K * 2;   // 39,168,000
    const size_t expTBytes = (size_t)CRF_K * CRF_K;                     //    360,000 (fp8)
    uint16_t* bp     = (uint16_t*)ws;
    uint32_t* expT8  = (uint32_t*)(ws + bpBytes);
    float*    rowmax = (float*)(ws + bpBytes + expTBytes);
    float*    rowmin = rowmax + CRF_K;
    float* scoreArr   = rowmin + CRF_K;
    float* lognormArr = scoreArr + CRF_B;
    int*   lastArr    = (int*)(lognormArr + CRF_B);

    prep_kernel<<<(CRF_K * CRF_K / 4 + 255) / 256, 256, 0, stream>>>(trans, expT8);
    prep2_kernel<<<CRF_K, 64, 0, stream>>>(trans, rowmax, rowmin);
    score_kernel<<<CRF_B, 64, 0, stream>>>(pot, trans, tags, seq_len, scoreArr);
    fwd_kernel<<<2 * CRF_B, FWD_NT, 61440, stream>>>(pot, trans, expT8, rowmax, rowmin,
                                                     seq_len, bp, lognormArr, lastArr);
    backtrace_kernel<<<(CRF_B + 63) / 64, 64, 0, stream>>>(bp, seq_len, lastArr, out);
    loss_kernel<<<1, 128, 0, stream>>>(scoreArr, lognormArr, out);
}